// Round 14
// baseline (157.095 us; speedup 1.0000x reference)
//
#include <hip/hip_runtime.h>
#include <hip/hip_bf16.h>

#define FIN   128
#define NH    8
#define NEG   0.2f
#define HB    256         // histogram/placement blocks (1 per CU)
#define NMAX  10240       // LDS cursor capacity / padded bin count
#define RSW   (NMAX / 2)  // packed row stride in uint words (5120)

typedef __attribute__((ext_vector_type(8))) short short8;   // 8 bf16 in 4 VGPRs
typedef __attribute__((ext_vector_type(4))) float f32x4;

// ---- helpers ----
__device__ __forceinline__ short f2bf(float f) {            // fp32 -> bf16 bits, RNE
    unsigned u = __float_as_uint(f);
    return (short)((u + 0x7FFFu + ((u >> 16) & 1u)) >> 16);
}
__device__ __forceinline__ float bflo(unsigned p) { return __uint_as_float(p << 16); }
__device__ __forceinline__ float bfhi(unsigned p) { return __uint_as_float(p & 0xFFFF0000u); }
__device__ __forceinline__ float ld_f(const void* p, int i, bool bf16) {
    if (bf16) {
        unsigned h = ((const unsigned short*)p)[i];
        return __uint_as_float(h << 16);
    }
    return ((const float*)p)[i];
}
__device__ __forceinline__ short8 ld_frag(const void* p, size_t off, bool bf16) {
    if (bf16) return *(const short8*)((const short*)p + off);
    const float* f = (const float*)p + off;
    f32x4 f0 = *(const f32x4*)f;
    f32x4 f1 = *(const f32x4*)(f + 4);
    short8 r;
    r[0] = f2bf(f0[0]); r[1] = f2bf(f0[1]); r[2] = f2bf(f0[2]); r[3] = f2bf(f0[3]);
    r[4] = f2bf(f1[0]); r[5] = f2bf(f1[1]); r[6] = f2bf(f1[2]); r[7] = f2bf(f1[3]);
    return r;
}
__device__ __forceinline__ float escore(float ss, float st) {
    float v = ss + st;
    v = v > 0.f ? v : NEG * v;                // leaky relu
    return __expf(fminf(v, 60.f));            // shift-free softmax numerator
}
// Per-wave dtype probes. All 64 lanes of the calling wave must be active.
__device__ __forceinline__ bool wave_bf16(const unsigned* x32) {
    unsigned w  = x32[threadIdx.x & 63];
    unsigned ex = (w >> 7) & 0xFFu;           // bf16 exponent of x[2*lane] if packed
    return __popcll(__ballot(ex >= 118u && ex <= 130u)) >= 48;
}
__device__ __forceinline__ bool wave_e64(const int* e32) {
    return __popcll(__ballot(e32[2 * (threadIdx.x & 63) + 1] == 0)) == 64;
}

// Kernel 1: per-block 16-bit packed LDS histogram of tgt. Paired edge loads:
// one int4 covers two int64 tgt words (.x/.z), one int2 two int32 ones.
__global__ __launch_bounds__(512) void k_hist(
    const int* __restrict__ e32, unsigned* __restrict__ hist2w,
    int N, int E, int perB)
{
    __shared__ unsigned l32[RSW];             // 20 KB: two 16-bit bins per word
    const bool e64 = wave_e64(e32);
    const int b = blockIdx.x, t = threadIdx.x;
    const int nw = (N + 1) >> 1;
    for (int j = t; j < nw; j += 512) l32[j] = 0;
    __syncthreads();
    const int lo = b * perB;
    const int hi = min(lo + perB, E);
    const int pairs = (hi - lo) >> 1;
    int ta[6], tb[6];
#pragma unroll
    for (int k = 0; k < 3; ++k) {             // preload pairs
        int p = t + k * 512;
        ta[k] = -1;
        if (p < pairs) {
            int i = lo + 2 * p;
            if (e64) {
                int4 v = *(const int4*)(e32 + 2 * ((size_t)E + i));
                ta[k] = v.x; tb[k] = v.z;
            } else {
                int2 v = *(const int2*)(e32 + (size_t)E + i);
                ta[k] = v.x; tb[k] = v.y;
            }
        }
    }
#pragma unroll
    for (int k = 0; k < 3; ++k)
        if (ta[k] >= 0) {
            atomicAdd(&l32[ta[k] >> 1], 1u << ((ta[k] & 1) << 4));
            atomicAdd(&l32[tb[k] >> 1], 1u << ((tb[k] & 1) << 4));
        }
    if (t == 0)                               // odd-length tail (unused: perB even)
        for (int i = lo + 2 * pairs; i < hi; ++i) {
            int tg = e64 ? ((const int2*)e32)[(size_t)E + i].x : e32[(size_t)E + i];
            atomicAdd(&l32[tg >> 1], 1u << ((tg & 1) << 4));
        }
    __syncthreads();
    const int nw4 = (nw + 3) >> 2;            // packed writeback, uint4
    uint4* dst = (uint4*)(hist2w + (size_t)b * RSW);
    const uint4* src = (const uint4*)l32;
    for (int j = t; j < nw4; j += 512) dst[j] = src[j];
}

// Kernel 2 (fused): blocks [0, csBlocks) = packed column-scan + sentinel-row
// init; blocks [csBlocks, ...) = the two GEMMs. No LDS in either role.
__global__ __launch_bounds__(256) void k_gemmscan(
    const void* __restrict__ x, const void* __restrict__ Wp,
    const void* __restrict__ Ws,
    const void* __restrict__ ssrcw, const void* __restrict__ stgtw,
    unsigned short* __restrict__ projb, unsigned short* __restrict__ skipb,
    float* __restrict__ s_src, float* __restrict__ s_tgt,
    const unsigned* __restrict__ hist2w, unsigned* __restrict__ pbase2w,
    unsigned* __restrict__ cnt2w,
    int N, int tiles, int halfTiles, int csBlocks)
{
    if ((int)blockIdx.x < csBlocks) {
        // sentinel row N: zero proj (so w*p == 0 exactly), -1e30 score (w = 0)
        if (blockIdx.x == 0) {
            if (threadIdx.x < FIN) projb[(size_t)N * FIN + threadIdx.x] = 0;
            if (threadIdx.x < NH)  s_src[(size_t)N * NH + threadIdx.x] = -1e30f;
        }
        const int j = blockIdx.x * 256 + threadIdx.x;   // word index (bin pair)
        if (j >= RSW) return;
        const int nw = (N + 1) >> 1;
        if (j >= nw) { cnt2w[j] = 0; return; }          // zero the pad words
        unsigned s0 = 0, s1 = 0;
#pragma unroll 8
        for (int r = 0; r < HB; ++r) {
            unsigned v = hist2w[(size_t)r * RSW + j];
            pbase2w[(size_t)r * RSW + j] = s0 | (s1 << 16);   // exclusive
            s0 += v & 0xFFFFu;
            s1 += v >> 16;
        }
        cnt2w[j] = s0 | (s1 << 16);
        return;
    }
    // ---- GEMM role ----
    const int wt = ((int)blockIdx.x - csBlocks) * 4 + ((int)threadIdx.x >> 6);
    if (wt >= tiles) return;
    const bool bf16 = wave_bf16((const unsigned*)x);
    const int lane = threadIdx.x & 63;
    const int mat = (wt >= halfTiles) ? 1 : 0;
    const int m0 = (mat ? wt - halfTiles : wt) * 16;
    const int mr = lane & 15;
    const int kb = lane >> 4;

    short8 a[4];
    const size_t xoff = (size_t)(m0 + mr) * FIN + kb * 8;
#pragma unroll
    for (int s = 0; s < 4; ++s) a[s] = ld_frag(x, xoff + s * 32, bf16);

    const void* W = mat ? Ws : Wp;
    f32x4 acc[8];
#pragma unroll
    for (int c = 0; c < 8; ++c) {
        acc[c] = (f32x4){0.f, 0.f, 0.f, 0.f};
        const size_t woff = (size_t)(c * 16 + mr) * FIN + kb * 8;
#pragma unroll
        for (int s = 0; s < 4; ++s) {
            short8 b = ld_frag(W, woff + s * 32, bf16);
            acc[c] = __builtin_amdgcn_mfma_f32_16x16x32_bf16(a[s], b, acc[c], 0, 0, 0);
        }
    }
    // D layout: col = lane&15, row = (lane>>4)*4 + r   [verified m89]
    if (mat == 0) {
#pragma unroll
        for (int c = 0; c < 8; ++c) {
            float sw = ld_f(ssrcw, c * 16 + mr, bf16);
            float tw = ld_f(stgtw, c * 16 + mr, bf16);
#pragma unroll
            for (int r = 0; r < 4; ++r) {
                int row = m0 + kb * 4 + r;
                float v = acc[c][r];
                projb[(size_t)row * FIN + c * 16 + mr] = (unsigned short)f2bf(v);
                float vs = v * sw, vt = v * tw;
#pragma unroll
                for (int o = 8; o >= 1; o >>= 1) {
                    vs += __shfl_xor(vs, o);
                    vt += __shfl_xor(vt, o);
                }
                if (mr == 0) {
                    s_src[row * NH + c] = vs;
                    s_tgt[row * NH + c] = vt;
                }
            }
        }
    } else {
#pragma unroll
        for (int c = 0; c < 8; ++c)
#pragma unroll
            for (int r = 0; r < 4; ++r)
                skipb[(size_t)(m0 + kb * 4 + r) * FIN + c * 16 + mr] =
                    (unsigned short)f2bf(acc[c][r]);
    }
}

// Kernel 3: placement with 8-PADDED bins. Redundant per-block scan over
// packed cnt/pbase (uint4, registers only); counts padded to multiples of 8
// so every CSR segment is 32B-aligned and a multiple of 8 long. Block 0
// publishes offs and fills the pad holes with sentinel node N (holes are
// never written by placement -> no race). Paired int4/int2 edge loads.
__global__ __launch_bounds__(256) void k_place(
    const int* __restrict__ e32, const unsigned* __restrict__ cnt2w,
    const unsigned* __restrict__ pbase2w, int* __restrict__ offs,
    int* __restrict__ sorted_src, int N, int E, int perB)
{
    __shared__ int cur[NMAX];
    __shared__ int sd[256];
    const bool e64 = wave_e64(e32);
    const int b = blockIdx.x, t = threadIdx.x;

    // ---- vectorized redundant scan: 20 packed words = 40 bins per thread ----
    {
        const uint4* c4 = (const uint4*)cnt2w + t * 5;
        uint4 v[5];
        int sum = 0;
#pragma unroll
        for (int q = 0; q < 5; ++q) {
            v[q] = c4[q];
            sum += (int)(((v[q].x & 0xFFFFu) + 7u) & ~7u) + (int)(((v[q].x >> 16) + 7u) & ~7u)
                 + (int)(((v[q].y & 0xFFFFu) + 7u) & ~7u) + (int)(((v[q].y >> 16) + 7u) & ~7u)
                 + (int)(((v[q].z & 0xFFFFu) + 7u) & ~7u) + (int)(((v[q].z >> 16) + 7u) & ~7u)
                 + (int)(((v[q].w & 0xFFFFu) + 7u) & ~7u) + (int)(((v[q].w >> 16) + 7u) & ~7u);
        }
        sd[t] = sum;
        __syncthreads();
#pragma unroll
        for (int off = 1; off < 256; off <<= 1) {
            int add = (t >= off) ? sd[t - off] : 0;
            __syncthreads();
            sd[t] += add;
            __syncthreads();
        }
        int run = sd[t] - sum;                // exclusive prefix (padded counts)
        const uint4* pb4 = (const uint4*)(pbase2w + (size_t)b * RSW) + t * 5;
        const int base = t * 40;
#pragma unroll
        for (int q = 0; q < 5; ++q) {
            uint4 pb = pb4[q];
            unsigned cw[4] = {v[q].x, v[q].y, v[q].z, v[q].w};
            unsigned pw[4] = {pb.x, pb.y, pb.z, pb.w};
#pragma unroll
            for (int u = 0; u < 4; ++u) {
                int idx = base + q * 8 + u * 2;
#pragma unroll
                for (int half = 0; half < 2; ++half) {
                    int c  = (int)((cw[u] >> (half * 16)) & 0xFFFFu);
                    int pbv = (int)((pw[u] >> (half * 16)) & 0xFFFFu);
                    int cp = (c + 7) & ~7;
                    cur[idx + half] = run + pbv;
                    if (b == 0) {
                        if (idx + half < N) offs[idx + half] = run;
                        for (int hgap = c; hgap < cp; ++hgap)
                            sorted_src[run + hgap] = N;   // sentinel fill
                    }
                    run += cp;
                }
            }
        }
        if (b == 0 && t == 255) offs[N] = run;
    }
    __syncthreads();

    // ---- placement: paired preload of all edge data, then atomic sweep ----
    const int lo = b * perB;
    const int hi = min(lo + perB, E);
    const int pairs = (hi - lo) >> 1;
    int sa[5], sb[5], ta[5], tb[5];
#pragma unroll
    for (int k = 0; k < 5; ++k) {
        int p = t + k * 256;
        ta[k] = -1;
        if (p < pairs) {
            int i = lo + 2 * p;
            if (e64) {
                int4 sv = *(const int4*)(e32 + 2 * (size_t)i);
                int4 tv = *(const int4*)(e32 + 2 * ((size_t)E + i));
                sa[k] = sv.x; sb[k] = sv.z; ta[k] = tv.x; tb[k] = tv.z;
            } else {
                int2 sv = *(const int2*)(e32 + (size_t)i);
                int2 tv = *(const int2*)(e32 + (size_t)E + i);
                sa[k] = sv.x; sb[k] = sv.y; ta[k] = tv.x; tb[k] = tv.y;
            }
        }
    }
#pragma unroll
    for (int k = 0; k < 5; ++k) {
        if (ta[k] >= 0) {
            int p0 = atomicAdd(&cur[ta[k]], 1);   // LDS atomics
            sorted_src[p0] = sa[k];
            int p1 = atomicAdd(&cur[tb[k]], 1);
            sorted_src[p1] = sb[k];
        }
    }
    if (t == 0)                               // odd tail (unused: perB even)
        for (int i = lo + 2 * pairs; i < hi; ++i) {
            int s, tg;
            if (e64) { s = ((const int2*)e32)[(size_t)i].x; tg = ((const int2*)e32)[(size_t)E + i].x; }
            else     { s = e32[i];                           tg = e32[(size_t)E + i]; }
            sorted_src[atomicAdd(&cur[tg], 1)] = s;
        }
}

// Kernel 4: 256-thread blocks, 4 nodes/block, one wave per node. Segments are
// 8-padded and 32B-aligned: exact groups of 8, NO tail loop, index prefetch
// via two int4 loads. Lane l owns column pair (2l, 2l+1), head l>>3; packed
// bf16x2 4B gather per edge; sentinel edges contribute exactly 0.
__global__ __launch_bounds__(256) void k_aggregate(
    const int* __restrict__ offs, const int* __restrict__ sorted_src,
    const float* __restrict__ s_src, const float* __restrict__ s_tgt,
    const unsigned short* __restrict__ projb, const unsigned short* __restrict__ skipb,
    const void* __restrict__ bias, void* __restrict__ out,
    const unsigned* __restrict__ x32, int N)
{
    const bool bf16 = wave_bf16(x32);
    const int n = blockIdx.x * 4 + ((int)threadIdx.x >> 6);
    if (n >= N) return;
    const int l = threadIdx.x & 63;
    const int start = offs[n], end = offs[n + 1];
    const int h = l >> 3;
    const int c2 = l * 2;
    const float st = s_tgt[(size_t)n * NH + h];

    float ae[8], ao[8], d[8];
#pragma unroll
    for (int k = 0; k < 8; ++k) { ae[k] = 0.f; ao[k] = 0.f; d[k] = 0.f; }

    const int cnt8 = (end - start) >> 3;      // exact: segments are 8-padded
    int e = start;
    if (cnt8 > 0) {
        int4 ia = *(const int4*)(sorted_src + e);
        int4 ib = *(const int4*)(sorted_src + e + 4);
        for (int g = 0; g < cnt8; ++g) {
            const int cu[8] = {ia.x, ia.y, ia.z, ia.w, ib.x, ib.y, ib.z, ib.w};
            e += 8;
            if (g + 1 < cnt8) {               // wave-uniform aligned prefetch
                ia = *(const int4*)(sorted_src + e);
                ib = *(const int4*)(sorted_src + e + 4);
            }
            unsigned p[8];
#pragma unroll
            for (int k = 0; k < 8; ++k)
                p[k] = *(const unsigned*)(projb + (size_t)cu[k] * FIN + c2);
            float w[8];
#pragma unroll
            for (int k = 0; k < 8; ++k)
                w[k] = escore(s_src[(size_t)cu[k] * NH + h], st);
#pragma unroll
            for (int k = 0; k < 8; ++k) {
                ae[k] += w[k] * bflo(p[k]);
                ao[k] += w[k] * bfhi(p[k]);
                d[k]  += w[k];
            }
        }
    }

    float num_e = ((ae[0] + ae[1]) + (ae[2] + ae[3])) + ((ae[4] + ae[5]) + (ae[6] + ae[7]));
    float num_o = ((ao[0] + ao[1]) + (ao[2] + ao[3])) + ((ao[4] + ao[5]) + (ao[6] + ao[7]));
    float den   = ((d[0] + d[1]) + (d[2] + d[3])) + ((d[4] + d[5]) + (d[6] + d[7]));
    float inv = 1.f / (den + 1e-16f);
    unsigned skp = *(const unsigned*)(skipb + (size_t)n * FIN + c2);
    float be, bo;
    if (bf16) {
        unsigned bb = *(const unsigned*)((const unsigned short*)bias + c2);
        be = bflo(bb); bo = bfhi(bb);
    } else {
        float2 b2 = *(const float2*)((const float*)bias + c2);
        be = b2.x; bo = b2.y;
    }
    float oe = num_e * inv + bflo(skp) + be;
    float oo = num_o * inv + bfhi(skp) + bo;
    if (bf16) {
        unsigned pr = ((unsigned)(unsigned short)f2bf(oo) << 16)
                    | (unsigned)(unsigned short)f2bf(oe);
        ((unsigned*)out)[((size_t)n * FIN + c2) >> 1] = pr;
    } else {
        float2 o2; o2.x = oe; o2.y = oo;
        *(float2*)((float*)out + (size_t)n * FIN + c2) = o2;
    }
}

extern "C" void kernel_launch(void* const* d_in, const int* in_sizes, int n_in,
                              void* d_out, int out_size, void* d_ws, size_t ws_size,
                              hipStream_t stream)
{
    const void* x    = d_in[0];
    const int* edges = (const int*)d_in[1];
    const void* Wp   = d_in[2];
    const void* Ws   = d_in[3];
    const void* ssw  = d_in[4];
    const void* stw  = d_in[5];
    const void* bias = d_in[6];

    const int N = in_sizes[0] / FIN;   // 10000
    const int E = in_sizes[1] / 2;     // 640000

    // workspace layout (256 B aligned; projb/s_src have a sentinel row N)
    char* wp = (char*)d_ws;
    auto takeB = [&wp](size_t bytes) {
        char* p = wp;
        wp += (bytes + 255) & ~(size_t)255;
        return p;
    };
    unsigned short* projb = (unsigned short*)takeB((size_t)(N + 1) * FIN * 2);
    unsigned short* skipb = (unsigned short*)takeB((size_t)N * FIN * 2);
    float* s_src      = (float*)takeB((size_t)(N + 1) * NH * 4);
    float* s_tgt      = (float*)takeB((size_t)N * NH * 4);
    int* sorted_src   = (int*)takeB(((size_t)E + 8 * N) * 4);   // 8-padded CSR
    int* offs         = (int*)takeB((size_t)(N + 8) * 4);
    unsigned* cnt2w   = (unsigned*)takeB((size_t)RSW * 4);
    unsigned* hist2w  = (unsigned*)takeB((size_t)HB * RSW * 4);
    unsigned* pbase2w = (unsigned*)takeB((size_t)HB * RSW * 4);

    const int halfTiles = (N + 15) / 16;         // 625
    const int tiles     = 2 * halfTiles;         // 1250
    const int gemmBlks  = (tiles + 3) / 4;       // 313
    const int csBlocks  = (RSW + 255) / 256;     // 20
    const int perB      = (E + HB - 1) / HB;     // 2500

    k_hist<<<HB, 512, 0, stream>>>(edges, hist2w, N, E, perB);
    k_gemmscan<<<csBlocks + gemmBlks, 256, 0, stream>>>(
        x, Wp, Ws, ssw, stw, projb, skipb, s_src, s_tgt,
        hist2w, pbase2w, cnt2w, N, tiles, halfTiles, csBlocks);
    k_place<<<HB, 256, 0, stream>>>(edges, cnt2w, pbase2w, offs, sorted_src, N, E, perB);
    k_aggregate<<<(N + 3) / 4, 256, 0, stream>>>(offs, sorted_src, s_src, s_tgt, projb,
                                                 skipb, bias, d_out, (const unsigned*)x, N);
}

// Round 15
// 135.259 us; speedup vs baseline: 1.1614x; 1.1614x over previous
//
#include <hip/hip_runtime.h>
#include <hip/hip_bf16.h>

#define FIN   128
#define NH    8
#define NEG   0.2f
#define HB    256         // histogram/placement blocks (1 per CU)
#define NMAX  10240       // LDS cursor capacity / padded bin count
#define RSW   (NMAX / 2)  // packed row stride in uint words (5120)

typedef __attribute__((ext_vector_type(8))) short short8;   // 8 bf16 in 4 VGPRs
typedef __attribute__((ext_vector_type(4))) float f32x4;

// ---- helpers ----
__device__ __forceinline__ short f2bf(float f) {            // fp32 -> bf16 bits, RNE
    unsigned u = __float_as_uint(f);
    return (short)((u + 0x7FFFu + ((u >> 16) & 1u)) >> 16);
}
__device__ __forceinline__ float bflo(unsigned p) { return __uint_as_float(p << 16); }
__device__ __forceinline__ float bfhi(unsigned p) { return __uint_as_float(p & 0xFFFF0000u); }
__device__ __forceinline__ float ld_f(const void* p, int i, bool bf16) {
    if (bf16) {
        unsigned h = ((const unsigned short*)p)[i];
        return __uint_as_float(h << 16);
    }
    return ((const float*)p)[i];
}
__device__ __forceinline__ short8 ld_frag(const void* p, size_t off, bool bf16) {
    if (bf16) return *(const short8*)((const short*)p + off);
    const float* f = (const float*)p + off;
    f32x4 f0 = *(const f32x4*)f;
    f32x4 f1 = *(const f32x4*)(f + 4);
    short8 r;
    r[0] = f2bf(f0[0]); r[1] = f2bf(f0[1]); r[2] = f2bf(f0[2]); r[3] = f2bf(f0[3]);
    r[4] = f2bf(f1[0]); r[5] = f2bf(f1[1]); r[6] = f2bf(f1[2]); r[7] = f2bf(f1[3]);
    return r;
}
__device__ __forceinline__ float escore(float ss, float st) {
    float v = ss + st;
    v = v > 0.f ? v : NEG * v;                // leaky relu
    return __expf(fminf(v, 60.f));            // shift-free softmax numerator
}
// Per-wave dtype probes. All 64 lanes of the calling wave must be active.
__device__ __forceinline__ bool wave_bf16(const unsigned* x32) {
    unsigned w  = x32[threadIdx.x & 63];
    unsigned ex = (w >> 7) & 0xFFu;           // bf16 exponent of x[2*lane] if packed
    return __popcll(__ballot(ex >= 118u && ex <= 130u)) >= 48;
}
__device__ __forceinline__ bool wave_e64(const int* e32) {
    return __popcll(__ballot(e32[2 * (threadIdx.x & 63) + 1] == 0)) == 64;
}

// Kernel 1: per-block 16-bit packed LDS histogram of tgt (per-block count
// <= perB=2500 < 2^16). Writeback is the RAW packed words — no unpack.
__global__ __launch_bounds__(256) void k_hist(
    const int* __restrict__ e32, unsigned* __restrict__ hist2w,
    int N, int E, int perB)
{
    __shared__ unsigned l32[RSW];             // 20 KB: two 16-bit bins per word
    const bool e64 = wave_e64(e32);
    const int b = blockIdx.x, t = threadIdx.x;
    const int nw = (N + 1) >> 1;
    for (int j = t; j < nw; j += 256) l32[j] = 0;
    __syncthreads();
    const int lo = b * perB;
    const int hi = min(lo + perB, E);
    for (int i = lo + t; i < hi; i += 256) {
        int tg = e64 ? ((const int2*)e32)[(size_t)E + i].x : e32[(size_t)E + i];
        atomicAdd(&l32[tg >> 1], 1u << ((tg & 1) << 4));   // LDS atomic
    }
    __syncthreads();
    // packed writeback, uint4-vectorized
    const int nw4 = (nw + 3) >> 2;            // 1250 for N=10000
    uint4* dst = (uint4*)(hist2w + (size_t)b * RSW);
    const uint4* src = (const uint4*)l32;
    for (int j = t; j < nw4; j += 256) dst[j] = src[j];
}

// Kernel 2 (fused): blocks [0, csBlocks) = packed column-scan (per-bin
// exclusive prefix across the HB hist rows; thread <-> bin-pair word,
// coalesced). Blocks [csBlocks, ...) = the two GEMMs (proj->bf16 + fused
// head scores; skip->bf16). Neither role uses LDS -> zero interference.
__global__ __launch_bounds__(256) void k_gemmscan(
    const void* __restrict__ x, const void* __restrict__ Wp,
    const void* __restrict__ Ws,
    const void* __restrict__ ssrcw, const void* __restrict__ stgtw,
    unsigned short* __restrict__ projb, unsigned short* __restrict__ skipb,
    float* __restrict__ s_src, float* __restrict__ s_tgt,
    const unsigned* __restrict__ hist2w, unsigned* __restrict__ pbase2w,
    unsigned* __restrict__ cnt2w,
    int N, int tiles, int halfTiles, int csBlocks)
{
    if ((int)blockIdx.x < csBlocks) {
        // ---- packed column scan ----
        const int j = blockIdx.x * 256 + threadIdx.x;   // word index (bin pair)
        if (j >= RSW) return;
        const int nw = (N + 1) >> 1;
        if (j >= nw) { cnt2w[j] = 0; return; }          // zero the pad words
        unsigned s0 = 0, s1 = 0;
#pragma unroll 8
        for (int r = 0; r < HB; ++r) {
            unsigned v = hist2w[(size_t)r * RSW + j];
            pbase2w[(size_t)r * RSW + j] = s0 | (s1 << 16);   // exclusive
            s0 += v & 0xFFFFu;
            s1 += v >> 16;
        }
        cnt2w[j] = s0 | (s1 << 16);
        return;
    }
    // ---- GEMM role ----
    const int wt = ((int)blockIdx.x - csBlocks) * 4 + ((int)threadIdx.x >> 6);
    if (wt >= tiles) return;
    const bool bf16 = wave_bf16((const unsigned*)x);
    const int lane = threadIdx.x & 63;
    const int mat = (wt >= halfTiles) ? 1 : 0;
    const int m0 = (mat ? wt - halfTiles : wt) * 16;
    const int mr = lane & 15;
    const int kb = lane >> 4;

    short8 a[4];
    const size_t xoff = (size_t)(m0 + mr) * FIN + kb * 8;
#pragma unroll
    for (int s = 0; s < 4; ++s) a[s] = ld_frag(x, xoff + s * 32, bf16);

    const void* W = mat ? Ws : Wp;
    f32x4 acc[8];
#pragma unroll
    for (int c = 0; c < 8; ++c) {
        acc[c] = (f32x4){0.f, 0.f, 0.f, 0.f};
        const size_t woff = (size_t)(c * 16 + mr) * FIN + kb * 8;
#pragma unroll
        for (int s = 0; s < 4; ++s) {
            short8 b = ld_frag(W, woff + s * 32, bf16);
            acc[c] = __builtin_amdgcn_mfma_f32_16x16x32_bf16(a[s], b, acc[c], 0, 0, 0);
        }
    }
    // D layout: col = lane&15, row = (lane>>4)*4 + r   [verified m89]
    if (mat == 0) {
#pragma unroll
        for (int c = 0; c < 8; ++c) {
            float sw = ld_f(ssrcw, c * 16 + mr, bf16);
            float tw = ld_f(stgtw, c * 16 + mr, bf16);
#pragma unroll
            for (int r = 0; r < 4; ++r) {
                int row = m0 + kb * 4 + r;
                float v = acc[c][r];
                projb[(size_t)row * FIN + c * 16 + mr] = (unsigned short)f2bf(v);
                float vs = v * sw, vt = v * tw;
#pragma unroll
                for (int o = 8; o >= 1; o >>= 1) {
                    vs += __shfl_xor(vs, o);
                    vt += __shfl_xor(vt, o);
                }
                if (mr == 0) {
                    s_src[row * NH + c] = vs;
                    s_tgt[row * NH + c] = vt;
                }
            }
        }
    } else {
#pragma unroll
        for (int c = 0; c < 8; ++c)
#pragma unroll
            for (int r = 0; r < 4; ++r)
                skipb[(size_t)(m0 + kb * 4 + r) * FIN + c * 16 + mr] =
                    (unsigned short)f2bf(acc[c][r]);
    }
}

// Kernel 3: placement. Redundant per-block offs-scan (zero inter-block
// communication — kernel boundary is the barrier) over the PACKED cnt/pbase:
// uint4 loads, prefix rebuilt in registers, no scratch arrays. Pad bins
// [N, NMAX) have cnt=0 so garbage pbase there is never consumed.
// Main loop: all (src,tgt) preloaded, then LDS-atomic rank + 4B store sweep.
// Block 0 publishes offs for k_aggregate.
__global__ __launch_bounds__(256) void k_place(
    const int* __restrict__ e32, const unsigned* __restrict__ cnt2w,
    const unsigned* __restrict__ pbase2w, int* __restrict__ offs,
    int* __restrict__ sorted_src, int N, int E, int perB)
{
    __shared__ int cur[NMAX];
    __shared__ int sd[256];
    const bool e64 = wave_e64(e32);
    const int b = blockIdx.x, t = threadIdx.x;

    // ---- vectorized redundant scan: 20 packed words = 40 bins per thread ----
    {
        const uint4* c4 = (const uint4*)cnt2w + t * 5;
        uint4 v[5];
        int sum = 0;
#pragma unroll
        for (int q = 0; q < 5; ++q) {
            v[q] = c4[q];
            sum += (int)((v[q].x & 0xFFFFu) + (v[q].x >> 16))
                 + (int)((v[q].y & 0xFFFFu) + (v[q].y >> 16))
                 + (int)((v[q].z & 0xFFFFu) + (v[q].z >> 16))
                 + (int)((v[q].w & 0xFFFFu) + (v[q].w >> 16));
        }
        sd[t] = sum;
        __syncthreads();
#pragma unroll
        for (int off = 1; off < 256; off <<= 1) {
            int add = (t >= off) ? sd[t - off] : 0;
            __syncthreads();
            sd[t] += add;
            __syncthreads();
        }
        int run = sd[t] - sum;                // exclusive prefix at this thread
        const uint4* pb4 = (const uint4*)(pbase2w + (size_t)b * RSW) + t * 5;
        const int base = t * 40;
#pragma unroll
        for (int q = 0; q < 5; ++q) {
            uint4 pb = pb4[q];
            unsigned cw[4] = {v[q].x, v[q].y, v[q].z, v[q].w};
            unsigned pw[4] = {pb.x, pb.y, pb.z, pb.w};
#pragma unroll
            for (int u = 0; u < 4; ++u) {
                int idx = base + q * 8 + u * 2;
                int c0 = (int)(cw[u] & 0xFFFFu), c1 = (int)(cw[u] >> 16);
                cur[idx] = run + (int)(pw[u] & 0xFFFFu);
                if (b == 0 && idx < N) offs[idx] = run;
                run += c0;
                cur[idx + 1] = run + (int)(pw[u] >> 16);
                if (b == 0 && idx + 1 < N) offs[idx + 1] = run;
                run += c1;
            }
        }
        if (b == 0 && t == 255) offs[N] = run;
    }
    __syncthreads();

    // ---- placement: preload all edge pairs, then atomic+store sweep ----
    const int lo = b * perB;
    const int hi = min(lo + perB, E);
    int se[10], te[10];
#pragma unroll
    for (int k = 0; k < 10; ++k) {
        int i = lo + t + k * 256;
        te[k] = -1;
        if (i < hi) {
            if (e64) {
                se[k] = ((const int2*)e32)[(size_t)i].x;
                te[k] = ((const int2*)e32)[(size_t)E + i].x;
            } else {
                se[k] = e32[i];
                te[k] = e32[(size_t)E + i];
            }
        }
    }
#pragma unroll
    for (int k = 0; k < 10; ++k) {
        if (te[k] >= 0) {
            int pos = atomicAdd(&cur[te[k]], 1);   // LDS atomic
            sorted_src[pos] = se[k];
        }
    }
    for (int i = lo + t + 10 * 256; i < hi; i += 256) {   // tail (unused at E=640k)
        int s, tg;
        if (e64) { s = ((const int2*)e32)[(size_t)i].x; tg = ((const int2*)e32)[(size_t)E + i].x; }
        else     { s = e32[i];                           tg = e32[(size_t)E + i]; }
        int pos = atomicAdd(&cur[tg], 1);
        sorted_src[pos] = s;
    }
}

// Kernel 4: one WAVE per node. Lane l owns column pair (2l, 2l+1) — both in
// head l>>3 — gathered as ONE packed bf16x2 4B load per edge. 8 independent
// gather chains + 8-wide index prefetch. Numerator and denominator accumulate
// in registers; skip+bias epilogue.
__global__ __launch_bounds__(64) void k_aggregate(
    const int* __restrict__ offs, const int* __restrict__ sorted_src,
    const float* __restrict__ s_src, const float* __restrict__ s_tgt,
    const unsigned short* __restrict__ projb, const unsigned short* __restrict__ skipb,
    const void* __restrict__ bias, void* __restrict__ out,
    const unsigned* __restrict__ x32)
{
    const bool bf16 = wave_bf16(x32);
    const int n = blockIdx.x, l = threadIdx.x;
    const int start = offs[n], end = offs[n + 1];
    const int h = l >> 3;
    const int c2 = l * 2;
    const float st = s_tgt[(size_t)n * NH + h];

    float ae[8], ao[8], d[8];
#pragma unroll
    for (int k = 0; k < 8; ++k) { ae[k] = 0.f; ao[k] = 0.f; d[k] = 0.f; }

    const int cnt8 = (end - start) >> 3;
    int e = start;
    if (cnt8 > 0) {
        int idx[8];
#pragma unroll
        for (int k = 0; k < 8; ++k) idx[k] = sorted_src[e + k];
        for (int g = 0; g < cnt8; ++g) {
            int cu[8];
#pragma unroll
            for (int k = 0; k < 8; ++k) cu[k] = idx[k];
            e += 8;
            if (g + 1 < cnt8) {               // wave-uniform prefetch
#pragma unroll
                for (int k = 0; k < 8; ++k) idx[k] = sorted_src[e + k];
            }
            unsigned p[8];
#pragma unroll
            for (int k = 0; k < 8; ++k)
                p[k] = *(const unsigned*)(projb + (size_t)cu[k] * FIN + c2);
            float w[8];
#pragma unroll
            for (int k = 0; k < 8; ++k)
                w[k] = escore(s_src[(size_t)cu[k] * NH + h], st);
#pragma unroll
            for (int k = 0; k < 8; ++k) {
                ae[k] += w[k] * bflo(p[k]);
                ao[k] += w[k] * bfhi(p[k]);
                d[k]  += w[k];
            }
        }
    }
    for (; e < end; ++e) {
        int s = sorted_src[e];
        float w = escore(s_src[(size_t)s * NH + h], st);
        unsigned p = *(const unsigned*)(projb + (size_t)s * FIN + c2);
        ae[0] += w * bflo(p); ao[0] += w * bfhi(p); d[0] += w;
    }

    float num_e = ((ae[0] + ae[1]) + (ae[2] + ae[3])) + ((ae[4] + ae[5]) + (ae[6] + ae[7]));
    float num_o = ((ao[0] + ao[1]) + (ao[2] + ao[3])) + ((ao[4] + ao[5]) + (ao[6] + ao[7]));
    float den   = ((d[0] + d[1]) + (d[2] + d[3])) + ((d[4] + d[5]) + (d[6] + d[7]));
    float inv = 1.f / (den + 1e-16f);
    unsigned skp = *(const unsigned*)(skipb + (size_t)n * FIN + c2);
    float be, bo;
    if (bf16) {
        unsigned bb = *(const unsigned*)((const unsigned short*)bias + c2);
        be = bflo(bb); bo = bfhi(bb);
    } else {
        float2 b2 = *(const float2*)((const float*)bias + c2);
        be = b2.x; bo = b2.y;
    }
    float oe = num_e * inv + bflo(skp) + be;
    float oo = num_o * inv + bfhi(skp) + bo;
    if (bf16) {
        unsigned pr = ((unsigned)(unsigned short)f2bf(oo) << 16)
                    | (unsigned)(unsigned short)f2bf(oe);
        ((unsigned*)out)[((size_t)n * FIN + c2) >> 1] = pr;
    } else {
        float2 o2; o2.x = oe; o2.y = oo;
        *(float2*)((float*)out + (size_t)n * FIN + c2) = o2;
    }
}

extern "C" void kernel_launch(void* const* d_in, const int* in_sizes, int n_in,
                              void* d_out, int out_size, void* d_ws, size_t ws_size,
                              hipStream_t stream)
{
    const void* x    = d_in[0];
    const int* edges = (const int*)d_in[1];
    const void* Wp   = d_in[2];
    const void* Ws   = d_in[3];
    const void* ssw  = d_in[4];
    const void* stw  = d_in[5];
    const void* bias = d_in[6];

    const int N = in_sizes[0] / FIN;   // 10000
    const int E = in_sizes[1] / 2;     // 640000

    // workspace layout (256 B aligned allocations)
    char* wp = (char*)d_ws;
    auto takeB = [&wp](size_t bytes) {
        char* p = wp;
        wp += (bytes + 255) & ~(size_t)255;
        return p;
    };
    unsigned short* projb = (unsigned short*)takeB((size_t)N * FIN * 2);
    unsigned short* skipb = (unsigned short*)takeB((size_t)N * FIN * 2);
    float* s_src      = (float*)takeB((size_t)N * NH * 4);
    float* s_tgt      = (float*)takeB((size_t)N * NH * 4);
    int* sorted_src   = (int*)takeB((size_t)E * 4);
    int* offs         = (int*)takeB((size_t)(N + 8) * 4);
    unsigned* cnt2w   = (unsigned*)takeB((size_t)RSW * 4);
    unsigned* hist2w  = (unsigned*)takeB((size_t)HB * RSW * 4);
    unsigned* pbase2w = (unsigned*)takeB((size_t)HB * RSW * 4);

    const int halfTiles = (N + 15) / 16;         // 625
    const int tiles     = 2 * halfTiles;         // 1250
    const int gemmBlks  = (tiles + 3) / 4;       // 313
    const int csBlocks  = (RSW + 255) / 256;     // 20
    const int perB      = (E + HB - 1) / HB;     // 2500

    k_hist<<<HB, 256, 0, stream>>>(edges, hist2w, N, E, perB);
    k_gemmscan<<<csBlocks + gemmBlks, 256, 0, stream>>>(
        x, Wp, Ws, ssw, stw, projb, skipb, s_src, s_tgt,
        hist2w, pbase2w, cnt2w, N, tiles, halfTiles, csBlocks);
    k_place<<<HB, 256, 0, stream>>>(edges, cnt2w, pbase2w, offs, sorted_src, N, E, perB);
    k_aggregate<<<N, 64, 0, stream>>>(offs, sorted_src, s_src, s_tgt, projb,
                                      skipb, bias, d_out, (const unsigned*)x);
}